// Round 4
// baseline (97.430 us; speedup 1.0000x reference)
//
#include <hip/hip_runtime.h>
#include <math.h>

namespace {
constexpr int R_RUNS  = 4096;
constexpr int T_STEPS = 2048;
constexpr int XDIM    = 8;
constexpr int ZDIM    = 8;
constexpr int RPB     = 8;               // runs per block (256 thr = 8 x 32)
constexpr int JCH     = 32;              // chunks per run (one per lane of 32-group)
constexpr int LC      = T_STEPS / JCH;   // 64 timesteps per chunk
}

__device__ __forceinline__ float sigmoidf_(float x) {
    return 1.0f / (1.0f + expf(-x));
}

__device__ __forceinline__ float dot8(const float* __restrict__ v, const float m[8]) {
    float s = 0.0f;
    #pragma unroll
    for (int i = 0; i < 8; ++i) s = fmaf(v[i], m[i], s);
    return s;
}

// ---------------------------------------------------------------------------
// One-pass fused kernel. Thread (r, j) owns run r, timesteps [64j, 64j+64).
// Phase A: chunk summary u_j = sum_i gh^{63-i} c_{t0+i},  c_t = b_{t-1}.
// Scan:    theta_start(j) = exclusive scan of u over the 32 lanes of the run
//          (Hillis-Steele with constant per-step multiplier A^d, A = gh^64).
// Phase C: replay chunk with output math, float4 stores.
// No LDS, no workspace, no second kernel, no grid sync.
// ---------------------------------------------------------------------------
extern "C" __global__ __launch_bounds__(256)
void dlm_onepass(const float* __restrict__ Xt, const float* __restrict__ Zt,
                 const float* __restrict__ G, const float* __restrict__ eta,
                 const float* __restrict__ zeta, const float* __restrict__ gamma,
                 float* __restrict__ out)
{
    const int tid = threadIdx.x;
    const int rl  = tid >> 5;                 // run within block, 0..7
    const int j   = tid & 31;                 // chunk index, 0..31
    const int r   = blockIdx.x * RPB + rl;
    const int t0  = j * LC;

    // ---- per-run params (32 lanes share r -> broadcast cache lines)
    const float4 g0 = *reinterpret_cast<const float4*>(gamma + (size_t)r * ZDIM);
    const float4 g1 = *reinterpret_cast<const float4*>(gamma + (size_t)r * ZDIM + 4);
    const float4 e0 = *reinterpret_cast<const float4*>(eta   + (size_t)r * XDIM);
    const float4 e1 = *reinterpret_cast<const float4*>(eta   + (size_t)r * XDIM + 4);
    const float4 z0 = *reinterpret_cast<const float4*>(zeta  + (size_t)r * ZDIM);
    const float4 z1 = *reinterpret_cast<const float4*>(zeta  + (size_t)r * ZDIM + 4);
    const float gm[8] = {g0.x, g0.y, g0.z, g0.w, g1.x, g1.y, g1.z, g1.w};
    const float et[8] = {e0.x, e0.y, e0.z, e0.w, e1.x, e1.y, e1.z, e1.w};
    const float zz[8] = {z0.x, z0.y, z0.z, z0.w, z1.x, z1.y, z1.z, z1.w};

    const float gh = sigmoidf_(G[r]);

    // ---- phase A: chunk summary (c_t = b_{t-1}; b_t = Z_t . gamma_r)
    float bb = 0.0f;
    if (j > 0) bb = dot8(Zt + (size_t)(t0 - 1) * ZDIM, gm);
    float u = 0.0f;
    #pragma unroll 4
    for (int i = 0; i < LC; ++i) {
        u = fmaf(gh, u, bb);                          // u = gh*u + c_{t0+i}
        bb = dot8(Zt + (size_t)(t0 + i) * ZDIM, gm);  // b_{t0+i}
    }

    // ---- A = gh^64
    float A = gh;
    #pragma unroll
    for (int i = 0; i < 6; ++i) A = A * A;

    // ---- in-register exclusive scan over 32 chunk summaries
    // inclusive Hillis-Steele: inc_j = theta_end(j); constant multiplier A^d.
    float inc = u;
    float p = A;
    #pragma unroll
    for (int d = 1; d < 32; d <<= 1) {
        const float up = __shfl_up(inc, (unsigned)d, 32);
        if (j >= d) inc = fmaf(p, up, inc);
        p = p * p;
    }
    float theta = __shfl_up(inc, 1u, 32);    // theta_end(j-1)
    if (j == 0) theta = 0.0f;

    // ---- phase C: replay with output math
    float bprev = 0.0f;
    if (j > 0) bprev = dot8(Zt + (size_t)(t0 - 1) * ZDIM, gm);

    float* __restrict__ orow = out + (size_t)r * T_STEPS + t0;
    #pragma unroll 2
    for (int grp = 0; grp < LC / 4; ++grp) {
        float4 acc;
        #pragma unroll
        for (int i = 0; i < 4; ++i) {
            const int t = t0 + grp * 4 + i;
            const float* __restrict__ x = Xt + (size_t)t * XDIM;
            const float* __restrict__ z = Zt + (size_t)t * ZDIM;
            float bx = 0.0f, bz = 0.0f, bn = 0.0f;
            #pragma unroll
            for (int q = 0; q < 8; ++q) {
                bx = fmaf(x[q], et[q], bx);
                bz = fmaf(z[q], zz[q], bz);
                bn = fmaf(z[q], gm[q], bn);
            }
            theta = fmaf(gh, theta, bprev);
            bprev = bn;
            const float v = theta + bx + bz;
            if (i == 0) acc.x = v;
            else if (i == 1) acc.y = v;
            else if (i == 2) acc.z = v;
            else acc.w = v;
        }
        *reinterpret_cast<float4*>(orow + grp * 4) = acc;
    }
}

// ---------------------------------------------------------------------------
extern "C" void kernel_launch(void* const* d_in, const int* in_sizes, int n_in,
                              void* d_out, int out_size, void* d_ws, size_t ws_size,
                              hipStream_t stream)
{
    const float* Xt    = (const float*)d_in[0];
    const float* Zt    = (const float*)d_in[1];
    const float* G     = (const float*)d_in[2];
    const float* eta   = (const float*)d_in[3];
    const float* zeta  = (const float*)d_in[4];
    const float* gamma = (const float*)d_in[5];
    float* out = (float*)d_out;

    const dim3 grid(R_RUNS / RPB);   // 512 blocks
    const dim3 blk(256);
    dlm_onepass<<<grid, blk, 0, stream>>>(Xt, Zt, G, eta, zeta, gamma, out);
}

// Round 5
// 57.213 us; speedup vs baseline: 1.7029x; 1.7029x over previous
//
#include <hip/hip_runtime.h>
#include <math.h>

namespace {
constexpr int R_RUNS   = 4096;
constexpr int T_STEPS  = 2048;
constexpr int XDIM     = 8;
constexpr int ZDIM     = 8;
constexpr int K_CHUNKS = 64;                 // chunks per run
constexpr int L_CHUNK  = T_STEPS / K_CHUNKS; // 32 timesteps per chunk
constexpr int NG       = R_RUNS / 64;        // 64 run-groups of 64 runs
constexpr int PAD_T    = L_CHUNK + 1;        // 33-word tile row stride: write (lane+j)%32 2-way,
                                             // read (rr+c)%32 2-way -> both conflict-free
}

__device__ __forceinline__ float sigmoidf_(float x) {
    return 1.0f / (1.0f + expf(-x));
}

__device__ __forceinline__ float dot8_lds(const float* __restrict__ row, const float m[8]) {
    // row points into LDS, 16B-aligned (32B rows); all lanes same address -> broadcast
    const float4 a = *reinterpret_cast<const float4*>(row);
    const float4 b = *reinterpret_cast<const float4*>(row + 4);
    float s;
    s = fmaf(a.x, m[0], a.y * m[1]);
    s = fmaf(a.z, m[2], s);
    s = fmaf(a.w, m[3], s);
    s = fmaf(b.x, m[4], s);
    s = fmaf(b.y, m[5], s);
    s = fmaf(b.z, m[6], s);
    s = fmaf(b.w, m[7], s);
    return s;
}

// ---------------------------------------------------------------------------
// Mapping (both kernels): wave = blockIdx*4 + wid
//   k = wave & 63  (chunk)   g = wave >> 6  (run group)
// -> a block's 4 waves: same g, consecutive k (k0 = (blockIdx*4)&63, k=k0+wid).
// Block stages Z rows [t0b-1, t0b+128) and (K3 only) X rows [t0b, t0b+128)
// into LDS with coalesced float4 loads; inner loops use LDS broadcasts.
// Row -1 is staged as zeros so the k==0 boundary needs no branch.
// ---------------------------------------------------------------------------

extern "C" __global__ __launch_bounds__(256, 4)
void dlm_k1_summary(const float* __restrict__ Zt, const float* __restrict__ G,
                    const float* __restrict__ gamma, float* __restrict__ U)
{
    __shared__ __align__(16) float zs[129 * 8];

    const int tid  = threadIdx.x;
    const int wid  = __builtin_amdgcn_readfirstlane((int)(tid >> 6));
    const int lane = tid & 63;
    const int k0   = (blockIdx.x * 4) & (K_CHUNKS - 1);
    const int g    = (blockIdx.x * 4) >> 6;
    const int k    = k0 + wid;
    const int r    = (g << 6) + lane;
    const int t0b  = k0 * L_CHUNK;

    // ---- stage Z rows [t0b-1, t0b+128) (129 rows = 258 float4)
    #pragma unroll
    for (int i = tid; i < 258; i += 256) {
        const int gidx = (t0b - 1) * ZDIM + i * 4;     // float index
        float4 v = make_float4(0.f, 0.f, 0.f, 0.f);
        if (gidx >= 0) v = *reinterpret_cast<const float4*>(Zt + gidx);
        *reinterpret_cast<float4*>(zs + i * 4) = v;
    }

    const float4 g0 = *reinterpret_cast<const float4*>(gamma + (size_t)r * ZDIM);
    const float4 g1 = *reinterpret_cast<const float4*>(gamma + (size_t)r * ZDIM + 4);
    const float gm[8] = {g0.x, g0.y, g0.z, g0.w, g1.x, g1.y, g1.z, g1.w};
    const float gh = sigmoidf_(G[r]);

    __syncthreads();

    // ---- chunk summary: u = sum_j gh^{31-j} b_{t0-1+j}
    float b_prev = dot8_lds(zs + (wid * 32) * ZDIM, gm);   // b_{t0-1} (zeros if k==0)
    float u = 0.0f;
    #pragma unroll
    for (int j = 0; j < L_CHUNK; ++j) {
        u = fmaf(gh, u, b_prev);
        b_prev = dot8_lds(zs + (wid * 32 + j + 1) * ZDIM, gm);
    }

    U[(size_t)k * R_RUNS + r] = u;
}

extern "C" __global__ __launch_bounds__(256, 3)
void dlm_k3_output(const float* __restrict__ Xt, const float* __restrict__ Zt,
                   const float* __restrict__ G, const float* __restrict__ eta,
                   const float* __restrict__ zeta, const float* __restrict__ gamma,
                   const float* __restrict__ U, float* __restrict__ out)
{
    __shared__ __align__(16) float zs[129 * 8];
    __shared__ __align__(16) float xs[128 * 8];
    __shared__ float tile[4][64][PAD_T];

    const int tid  = threadIdx.x;
    const int wid  = __builtin_amdgcn_readfirstlane((int)(tid >> 6));
    const int lane = tid & 63;
    const int k0   = (blockIdx.x * 4) & (K_CHUNKS - 1);
    const int g    = (blockIdx.x * 4) >> 6;
    const int k    = k0 + wid;
    const int r    = (g << 6) + lane;
    const int t0b  = k0 * L_CHUNK;

    // ---- stage Z [t0b-1, t0b+128) and X [t0b, t0b+128)
    #pragma unroll
    for (int i = tid; i < 258; i += 256) {
        const int gidx = (t0b - 1) * ZDIM + i * 4;
        float4 v = make_float4(0.f, 0.f, 0.f, 0.f);
        if (gidx >= 0) v = *reinterpret_cast<const float4*>(Zt + gidx);
        *reinterpret_cast<float4*>(zs + i * 4) = v;
    }
    *reinterpret_cast<float4*>(xs + tid * 4) =
        *reinterpret_cast<const float4*>(Xt + (size_t)t0b * XDIM + tid * 4);

    // ---- per-run params (overlap with staging)
    const float4 g0 = *reinterpret_cast<const float4*>(gamma + (size_t)r * ZDIM);
    const float4 g1 = *reinterpret_cast<const float4*>(gamma + (size_t)r * ZDIM + 4);
    const float4 e0 = *reinterpret_cast<const float4*>(eta   + (size_t)r * XDIM);
    const float4 e1 = *reinterpret_cast<const float4*>(eta   + (size_t)r * XDIM + 4);
    const float4 z0 = *reinterpret_cast<const float4*>(zeta  + (size_t)r * ZDIM);
    const float4 z1 = *reinterpret_cast<const float4*>(zeta  + (size_t)r * ZDIM + 4);
    const float gm[8] = {g0.x, g0.y, g0.z, g0.w, g1.x, g1.y, g1.z, g1.w};
    const float et[8] = {e0.x, e0.y, e0.z, e0.w, e1.x, e1.y, e1.z, e1.w};
    const float zz[8] = {z0.x, z0.y, z0.z, z0.w, z1.x, z1.y, z1.z, z1.w};
    const float gh = sigmoidf_(G[r]);

    // ---- theta at t0-1: prefix over chunk summaries (global U, coalesced)
    float A = gh;
    #pragma unroll
    for (int i = 0; i < 5; ++i) A = A * A;   // gh^32
    float theta = 0.0f;
    for (int j = 0; j < k; ++j)
        theta = fmaf(A, theta, U[(size_t)j * R_RUNS + r]);

    __syncthreads();

    // ---- replay chunk with output math (all X/Z from LDS broadcasts)
    float b_prev = dot8_lds(zs + (wid * 32) * ZDIM, gm);   // b_{t0-1} (zeros if k==0)
    #pragma unroll
    for (int j = 0; j < L_CHUNK; ++j) {
        const float* __restrict__ zr = zs + (wid * 32 + j + 1) * ZDIM;
        const float* __restrict__ xr = xs + (wid * 32 + j) * XDIM;
        const float4 za = *reinterpret_cast<const float4*>(zr);
        const float4 zb = *reinterpret_cast<const float4*>(zr + 4);
        const float4 xa = *reinterpret_cast<const float4*>(xr);
        const float4 xb = *reinterpret_cast<const float4*>(xr + 4);

        float bx = xa.x * et[0], bz = za.x * zz[0], bn = za.x * gm[0];
        bx = fmaf(xa.y, et[1], bx); bz = fmaf(za.y, zz[1], bz); bn = fmaf(za.y, gm[1], bn);
        bx = fmaf(xa.z, et[2], bx); bz = fmaf(za.z, zz[2], bz); bn = fmaf(za.z, gm[2], bn);
        bx = fmaf(xa.w, et[3], bx); bz = fmaf(za.w, zz[3], bz); bn = fmaf(za.w, gm[3], bn);
        bx = fmaf(xb.x, et[4], bx); bz = fmaf(zb.x, zz[4], bz); bn = fmaf(zb.x, gm[4], bn);
        bx = fmaf(xb.y, et[5], bx); bz = fmaf(zb.y, zz[5], bz); bn = fmaf(zb.y, gm[5], bn);
        bx = fmaf(xb.z, et[6], bx); bz = fmaf(zb.z, zz[6], bz); bn = fmaf(zb.z, gm[6], bn);
        bx = fmaf(xb.w, et[7], bx); bz = fmaf(zb.w, zz[7], bz); bn = fmaf(zb.w, gm[7], bn);

        theta = fmaf(gh, theta, b_prev);
        b_prev = bn;
        tile[wid][lane][j] = theta + bx + bz;
    }

    // ---- flush (wave-private tile: no block barrier needed).
    // Per instr: 2 rows x 128B contiguous; block covers a 512B window per row.
    const int rr_half = lane >> 5;
    const int c       = lane & 31;
    #pragma unroll
    for (int it = 0; it < 32; ++it) {
        const int rr = it * 2 + rr_half;
        const float v = tile[wid][rr][c];
        out[(size_t)((g << 6) + rr) * T_STEPS + k * L_CHUNK + c] = v;
    }
}

// ---------------------------------------------------------------------------
extern "C" void kernel_launch(void* const* d_in, const int* in_sizes, int n_in,
                              void* d_out, int out_size, void* d_ws, size_t ws_size,
                              hipStream_t stream)
{
    const float* Xt    = (const float*)d_in[0];
    const float* Zt    = (const float*)d_in[1];
    const float* G     = (const float*)d_in[2];
    const float* eta   = (const float*)d_in[3];
    const float* zeta  = (const float*)d_in[4];
    const float* gamma = (const float*)d_in[5];
    float* out = (float*)d_out;

    float* U = (float*)d_ws;                  // U[K][R], 1 MB

    const dim3 blk(256);
    const dim3 grid(NG * K_CHUNKS / 4);       // 1024 blocks (4 waves each)

    dlm_k1_summary<<<grid, blk, 0, stream>>>(Zt, G, gamma, U);
    dlm_k3_output <<<grid, blk, 0, stream>>>(Xt, Zt, G, eta, zeta, gamma, U, out);
}